// Round 7
// baseline (171.390 us; speedup 1.0000x reference)
//
#include <hip/hip_runtime.h>

typedef __bf16 bf16x8 __attribute__((ext_vector_type(8)));
typedef float f32x4 __attribute__((ext_vector_type(4)));
typedef unsigned short u16;
typedef unsigned int u32;

__device__ __forceinline__ u16 f2bf(float f) {
  u32 u = __builtin_bit_cast(u32, f);
  u32 r = (u + 0x7FFFu + ((u >> 16) & 1u)) >> 16;
  return (u16)r;
}

__device__ __forceinline__ void gload_lds16(const u16* g, u16* l) {
  __builtin_amdgcn_global_load_lds(
      (const __attribute__((address_space(1))) u32*)g,
      (__attribute__((address_space(3))) u32*)l, 16, 0, 0);
}

// ---------------- pre-pass: cast x to bf16 ----------------
__global__ void cast_x_kernel(const float* __restrict__ in, u16* __restrict__ out, int n4) {
  int i = blockIdx.x * blockDim.x + threadIdx.x;
  if (i >= n4) return;
  float4 v = ((const float4*)in)[i];
  uint2 o;
  o.x = (u32)f2bf(v.x) | ((u32)f2bf(v.y) << 16);
  o.y = (u32)f2bf(v.z) | ((u32)f2bf(v.w) << 16);
  ((uint2*)out)[i] = o;
}

// ---------------- pre-pass: transpose+cast weights [K][N] -> [N][K] bf16 ----
__global__ void transpose_cast_kernel(const float* __restrict__ in, u16* __restrict__ out,
                                      int K, int N) {
  __shared__ float tile[32][33];
  int n0 = blockIdx.x * 32, k0 = blockIdx.y * 32;
  int tx = threadIdx.x & 31, ty = threadIdx.x >> 5;  // ty 0..7
#pragma unroll
  for (int i = 0; i < 32; i += 8)
    tile[ty + i][tx] = in[(size_t)(k0 + ty + i) * N + n0 + tx];
  __syncthreads();
#pragma unroll
  for (int i = 0; i < 32; i += 8)
    out[(size_t)(n0 + ty + i) * K + k0 + tx] = f2bf(tile[tx][ty + i]);
}

// ---------------- 128x128 2-phase GEMM: A[M][K] bf16 @ Bt[N][K] bf16 + bias --
// Swizzle: chunk = lg ^ (row&3) ^ ((row>>2)&3)  -> <=2-way bank alias (free).
// MODE 0: operand-SWAPPED mfma (D[row]=ncol, D[col]=token) so each lane holds
//         4 consecutive d values -> packed 8B stores into Q/K/V [B][H][T][64].
// MODE 1: normal orientation, coalesced f32 row-major store.
template <int MODE>
__global__ __launch_bounds__(256, 3) void gemm_bf16(
    const u16* __restrict__ A, const u16* __restrict__ Bt,
    const float* __restrict__ bias, u16* __restrict__ out_q,
    float* __restrict__ out_f, int M, int N, int K) {
  __shared__ alignas(16) u16 As[128 * 32];
  __shared__ alignas(16) u16 Bs[128 * 32];
  const int tiles_n = N >> 7;
  const int bid0 = blockIdx.x;
  const int cpx = (int)gridDim.x >> 3;            // grid % 8 == 0
  const int swz = (bid0 & 7) * cpx + (bid0 >> 3); // XCD-bijective swizzle
  const int tm = swz / tiles_n;
  const int tn = swz % tiles_n;
  const int tid = threadIdx.x;
  const int wave = tid >> 6, lane = tid & 63;
  const int wr = (wave >> 1) * 64, wc = (wave & 1) * 64;
  const int lr = lane & 15, lg = lane >> 4;

  f32x4 acc[4][4] = {};
  const size_t a_base = (size_t)(tm * 128) * K;
  const size_t b_base = (size_t)(tn * 128) * K;

  for (int k0 = 0; k0 < K; k0 += 32) {
#pragma unroll
    for (int i = 0; i < 2; ++i) {
      int flat = i * 256 + tid;
      int row = flat >> 2, ch = flat & 3;
      int sw = (ch ^ (row & 3) ^ ((row >> 2) & 3)) * 8;  // inverse swizzle on source
      gload_lds16(A + a_base + (size_t)row * K + k0 + sw, &As[flat * 8]);
      gload_lds16(Bt + b_base + (size_t)row * K + k0 + sw, &Bs[flat * 8]);
    }
    __syncthreads();
    bf16x8 af[4], bfr[4];
#pragma unroll
    for (int m = 0; m < 4; ++m) {
      int row = wr + m * 16 + lr;
      af[m] = *(const bf16x8*)&As[row * 32 + ((lg ^ (row & 3) ^ ((row >> 2) & 3)) * 8)];
    }
#pragma unroll
    for (int n = 0; n < 4; ++n) {
      int row = wc + n * 16 + lr;
      bfr[n] = *(const bf16x8*)&Bs[row * 32 + ((lg ^ (row & 3) ^ ((row >> 2) & 3)) * 8)];
    }
#pragma unroll
    for (int m = 0; m < 4; ++m)
#pragma unroll
      for (int n = 0; n < 4; ++n) {
        if constexpr (MODE == 0)
          acc[m][n] = __builtin_amdgcn_mfma_f32_16x16x32_bf16(bfr[n], af[m], acc[m][n], 0, 0, 0);
        else
          acc[m][n] = __builtin_amdgcn_mfma_f32_16x16x32_bf16(af[m], bfr[n], acc[m][n], 0, 0, 0);
      }
    __syncthreads();
  }

  if constexpr (MODE == 0) {
    // D[row=ncol][col=token]: lane holds token = m*16+lr (fixed), d = n*16+lg*4+r
    const int tok0 = tm * 128 + wr;
    const int col0 = tn * 128 + wc;
#pragma unroll
    for (int n = 0; n < 4; ++n) {
      int ncol = col0 + n * 16 + lg * 4;
      float4 bv = *(const float4*)&bias[ncol];
      int which = ncol >> 10, c = ncol & 1023;
      int h = c >> 6, d = c & 63;
#pragma unroll
      for (int m = 0; m < 4; ++m) {
        int tok = tok0 + m * 16 + lr;
        int b = tok >> 10, t = tok & 1023;
        union { u16 s[4]; uint2 v; } pk;
        pk.s[0] = f2bf(acc[m][n][0] + bv.x);
        pk.s[1] = f2bf(acc[m][n][1] + bv.y);
        pk.s[2] = f2bf(acc[m][n][2] + bv.z);
        pk.s[3] = f2bf(acc[m][n][3] + bv.w);
        *(uint2*)&out_q[(size_t)which * 8388608 + ((((size_t)b * 16 + h) * 1024 + t) << 6) + d] = pk.v;
      }
    }
  } else {
    const int row0 = tm * 128 + wr;
    const int col0 = tn * 128 + wc;
#pragma unroll
    for (int n = 0; n < 4; ++n) {
      int col = col0 + n * 16 + lr;
      float bv = bias[col];
#pragma unroll
      for (int m = 0; m < 4; ++m)
#pragma unroll
        for (int r = 0; r < 4; ++r) {
          int mrow = row0 + m * 16 + lg * 4 + r;
          out_f[(size_t)mrow * N + col] = acc[m][n][r] + bv;
        }
    }
  }
}

// ---------------- flash attention v2: swapped QK^T + paired q-tiles --------
__global__ __launch_bounds__(256, 2) void attn_kernel(
    const u16* __restrict__ Qb, const u16* __restrict__ Kb,
    const u16* __restrict__ Vb, u16* __restrict__ yb) {
  __shared__ alignas(16) u16 Ks[64 * 64];
  __shared__ alignas(16) u16 Vt[64 * 64];
  __shared__ alignas(16) u16 Pl[4][32 * 64];
  __shared__ float abuf[4][32];

  const int bid = blockIdx.x;
  const int xcd = bid & 7, j = bid >> 3;
  const int bh = ((j >> 2) << 3) + xcd;
  const int pr = j & 3;
  const size_t hb = (size_t)bh * 65536;
  const int tid = threadIdx.x, w = tid >> 6, lane = tid & 63;
  const int lr = lane & 15, lg = lane >> 4;
  const int b = bh >> 4, h = bh & 15;

  for (int pass = 0; pass < 2; ++pass) {
    const int qt = pass ? (7 - pr) : pr;
    const int q0 = qt * 128 + w * 32;

    bf16x8 qf[2][2];
#pragma unroll
    for (int mi = 0; mi < 2; ++mi)
#pragma unroll
      for (int ks = 0; ks < 2; ++ks)
        qf[mi][ks] = *(const bf16x8*)&Qb[hb + (size_t)(q0 + mi * 16 + lr) * 64 + ks * 32 + lg * 8];

    float m_run[2] = {-1e30f, -1e30f}, l_run[2] = {0.f, 0.f};
    f32x4 o[2][4] = {};

    const int nkt = (qt + 1) * 2;
    for (int kt = 0; kt < nkt; ++kt) {
#pragma unroll
      for (int i = 0; i < 2; ++i) {
        int flat = i * 256 + tid;
        int row = flat >> 3, ch = flat & 7;
        gload_lds16(Kb + hb + (size_t)(kt * 64 + row) * 64 + ((ch ^ (row & 7)) * 8), &Ks[flat * 8]);
      }
      {
        int key = tid & 63, d0 = (tid >> 6) * 16;
        const u16* src = Vb + hb + (size_t)(kt * 64 + key) * 64 + d0;
        union { uint4 v[2]; u16 s[16]; } tmp;
        tmp.v[0] = *(const uint4*)src;
        tmp.v[1] = *(const uint4*)(src + 8);
#pragma unroll
        for (int jj = 0; jj < 16; ++jj) {
          int d = d0 + jj;
          Vt[d * 64 + (key ^ ((d & 7) << 3))] = tmp.s[jj];
        }
      }
      __syncthreads();

      if (kt * 64 <= q0 + 31) {
        f32x4 s[4][2] = {};
        __builtin_amdgcn_s_setprio(1);
#pragma unroll
        for (int ni = 0; ni < 4; ++ni) {
          int krow = ni * 16 + lr;
          bf16x8 kf0 = *(const bf16x8*)&Ks[krow * 64 + ((lg ^ (krow & 7)) * 8)];
          bf16x8 kf1 = *(const bf16x8*)&Ks[krow * 64 + (((4 + lg) ^ (krow & 7)) * 8)];
#pragma unroll
          for (int mi = 0; mi < 2; ++mi) {
            s[ni][mi] = __builtin_amdgcn_mfma_f32_16x16x32_bf16(kf0, qf[mi][0], s[ni][mi], 0, 0, 0);
            s[ni][mi] = __builtin_amdgcn_mfma_f32_16x16x32_bf16(kf1, qf[mi][1], s[ni][mi], 0, 0, 0);
          }
        }
        __builtin_amdgcn_s_setprio(0);

        const bool need_mask = (kt * 64 + 63) > q0;
        float alpha_l[2];
#pragma unroll
        for (int mi = 0; mi < 2; ++mi) {
          float v = -1e30f;
#pragma unroll
          for (int ni = 0; ni < 4; ++ni)
#pragma unroll
            for (int r = 0; r < 4; ++r) {
              float sv = s[ni][mi][r];
              if (need_mask) {
                int ka = kt * 64 + ni * 16 + lg * 4 + r;
                int qa = q0 + mi * 16 + lr;
                if (ka > qa) sv = -1e30f;
              }
              s[ni][mi][r] = sv;
              v = fmaxf(v, sv);
            }
          v = fmaxf(v, __shfl_xor(v, 16));
          v = fmaxf(v, __shfl_xor(v, 32));
          float mn = fmaxf(m_run[mi], v);
          float al = __expf((m_run[mi] - mn) * 0.125f);
          m_run[mi] = mn;
          float mh = mn * 0.125f;
          float rs = 0.f;
#pragma unroll
          for (int ni = 0; ni < 4; ++ni)
#pragma unroll
            for (int r = 0; r < 4; ++r) {
              float p = __expf(s[ni][mi][r] * 0.125f - mh);
              s[ni][mi][r] = p;
              rs += p;
            }
          rs += __shfl_xor(rs, 16);
          rs += __shfl_xor(rs, 32);
          l_run[mi] = l_run[mi] * al + rs;
          alpha_l[mi] = al;
        }
        if (lg == 0) {
          abuf[w][lr] = alpha_l[0];
          abuf[w][16 + lr] = alpha_l[1];
        }
#pragma unroll
        for (int mi = 0; mi < 2; ++mi) {
          int qrow = mi * 16 + lr;
          u16* dst = &Pl[w][qrow * 64];
          int sw = (qrow & 7) << 3;
#pragma unroll
          for (int ni = 0; ni < 4; ++ni)
#pragma unroll
            for (int r = 0; r < 4; ++r)
              dst[(ni * 16 + lg * 4 + r) ^ sw] = f2bf(s[ni][mi][r]);
        }
        asm volatile("s_waitcnt lgkmcnt(0)" ::: "memory");
#pragma unroll
        for (int mi = 0; mi < 2; ++mi) {
          f32x4 av;
#pragma unroll
          for (int r = 0; r < 4; ++r) av[r] = abuf[w][mi * 16 + lg * 4 + r];
#pragma unroll
          for (int nd = 0; nd < 4; ++nd)
#pragma unroll
            for (int r = 0; r < 4; ++r) o[mi][nd][r] *= av[r];
        }
        __builtin_amdgcn_s_setprio(1);
#pragma unroll
        for (int ks = 0; ks < 2; ++ks) {
          bf16x8 pf[2];
#pragma unroll
          for (int mi = 0; mi < 2; ++mi) {
            int prow = mi * 16 + lr;
            pf[mi] = *(const bf16x8*)&Pl[w][prow * 64 + (((ks * 4 + lg) ^ (prow & 7)) * 8)];
          }
#pragma unroll
          for (int nd = 0; nd < 4; ++nd) {
            int vrow = nd * 16 + lr;
            bf16x8 vf = *(const bf16x8*)&Vt[vrow * 64 + (((ks * 4 + lg) ^ (vrow & 7)) * 8)];
#pragma unroll
            for (int mi = 0; mi < 2; ++mi)
              o[mi][nd] = __builtin_amdgcn_mfma_f32_16x16x32_bf16(pf[mi], vf, o[mi][nd], 0, 0, 0);
          }
        }
        __builtin_amdgcn_s_setprio(0);
      }
      __syncthreads();
    }

    if (lg == 0) {
      abuf[w][lr] = l_run[0];
      abuf[w][16 + lr] = l_run[1];
    }
    asm volatile("s_waitcnt lgkmcnt(0)" ::: "memory");
#pragma unroll
    for (int mi = 0; mi < 2; ++mi) {
      f32x4 inv;
#pragma unroll
      for (int r = 0; r < 4; ++r) inv[r] = 1.f / abuf[w][mi * 16 + lg * 4 + r];
#pragma unroll
      for (int nd = 0; nd < 4; ++nd)
#pragma unroll
        for (int r = 0; r < 4; ++r) {
          int t = q0 + mi * 16 + lg * 4 + r;
          int c = h * 64 + nd * 16 + lr;
          yb[((size_t)b * 1024 + t) * 1024 + c] = f2bf(o[mi][nd][r] * inv[r]);
        }
    }
    __syncthreads();
  }
}

extern "C" void kernel_launch(void* const* d_in, const int* in_sizes, int n_in,
                              void* d_out, int out_size, void* d_ws, size_t ws_size,
                              hipStream_t stream) {
  const float* x = (const float*)d_in[0];
  const float* w_attn = (const float*)d_in[1];
  const float* b_attn = (const float*)d_in[2];
  const float* w_proj = (const float*)d_in[3];
  const float* b_proj = (const float*)d_in[4];
  float* out = (float*)d_out;

  u16* ws = (u16*)d_ws;
  u16* xb = ws;                  // 8192*1024 bf16 (reused as y after GEMM1)
  u16* watT = xb + 8388608;      // 3072*1024
  u16* wpT = watT + 3145728;     // 1024*1024
  u16* Qb = wpT + 1048576;       // 3 x 8388608 (Q,K,V contiguous)
  u16* yb = xb;

  cast_x_kernel<<<8192, 256, 0, stream>>>(x, xb, 2097152);
  {
    dim3 g(96, 32);
    transpose_cast_kernel<<<g, 256, 0, stream>>>(w_attn, watT, 1024, 3072);
  }
  {
    dim3 g(32, 32);
    transpose_cast_kernel<<<g, 256, 0, stream>>>(w_proj, wpT, 1024, 1024);
  }
  gemm_bf16<0><<<64 * 24, 256, 0, stream>>>(xb, watT, b_attn, Qb, nullptr, 8192, 3072, 1024);
  attn_kernel<<<512, 256, 0, stream>>>(Qb, Qb + 8388608, Qb + 2 * 8388608, yb);
  gemm_bf16<1><<<64 * 8, 256, 0, stream>>>(yb, wpT, b_proj, nullptr, out, 8192, 1024, 1024);
}

// Round 8
// 169.514 us; speedup vs baseline: 1.0111x; 1.0111x over previous
//
#include <hip/hip_runtime.h>

typedef __bf16 bf16x8 __attribute__((ext_vector_type(8)));
typedef float f32x4 __attribute__((ext_vector_type(4)));
typedef unsigned short u16;
typedef unsigned int u32;

__device__ __forceinline__ u16 f2bf(float f) {
  u32 u = __builtin_bit_cast(u32, f);
  u32 r = (u + 0x7FFFu + ((u >> 16) & 1u)) >> 16;
  return (u16)r;
}

__device__ __forceinline__ void gload_lds16(const u16* g, u16* l) {
  __builtin_amdgcn_global_load_lds(
      (const __attribute__((address_space(1))) u32*)g,
      (__attribute__((address_space(3))) u32*)l, 16, 0, 0);
}

// ---------------- pre-pass: cast x to bf16 ----------------
__global__ void cast_x_kernel(const float* __restrict__ in, u16* __restrict__ out, int n4) {
  int i = blockIdx.x * blockDim.x + threadIdx.x;
  if (i >= n4) return;
  float4 v = ((const float4*)in)[i];
  uint2 o;
  o.x = (u32)f2bf(v.x) | ((u32)f2bf(v.y) << 16);
  o.y = (u32)f2bf(v.z) | ((u32)f2bf(v.w) << 16);
  ((uint2*)out)[i] = o;
}

// ---------------- pre-pass: transpose+cast weights [K][N] -> [N][K] bf16 ----
__global__ void transpose_cast_kernel(const float* __restrict__ in, u16* __restrict__ out,
                                      int K, int N) {
  __shared__ float tile[32][33];
  int n0 = blockIdx.x * 32, k0 = blockIdx.y * 32;
  int tx = threadIdx.x & 31, ty = threadIdx.x >> 5;  // ty 0..7
#pragma unroll
  for (int i = 0; i < 32; i += 8)
    tile[ty + i][tx] = in[(size_t)(k0 + ty + i) * N + n0 + tx];
  __syncthreads();
#pragma unroll
  for (int i = 0; i < 32; i += 8)
    out[(size_t)(n0 + ty + i) * K + k0 + tx] = f2bf(tile[tx][ty + i]);
}

// ---------------- 128x128 GEMM, BK=64: A[M][K] bf16 @ Bt[N][K] bf16 + bias --
// LDS row stride 128 B + chunk^=(row&7) swizzle = 0 bank conflicts
// (empirically verified in the gemm256 probe: SQ_LDS_BANK_CONFLICT == 0).
// MODE 0: operand-SWAPPED mfma so lanes hold 4 consecutive d -> 8B packed
//         stores into Q/K/V [B][H][T][64]. MODE 1: f32 row-major store.
template <int MODE>
__global__ __launch_bounds__(256, 3) void gemm_bf16(
    const u16* __restrict__ A, const u16* __restrict__ Bt,
    const float* __restrict__ bias, u16* __restrict__ out_q,
    float* __restrict__ out_f, int M, int N, int K) {
  __shared__ alignas(16) u16 As[128 * 64];
  __shared__ alignas(16) u16 Bs[128 * 64];
  const int tiles_n = N >> 7;
  const int bid0 = blockIdx.x;
  const int cpx = (int)gridDim.x >> 3;            // grid % 8 == 0
  const int swz = (bid0 & 7) * cpx + (bid0 >> 3); // XCD-bijective swizzle
  const int tm = swz / tiles_n;
  const int tn = swz % tiles_n;
  const int tid = threadIdx.x;
  const int wave = tid >> 6, lane = tid & 63;
  const int wr = (wave >> 1) * 64, wc = (wave & 1) * 64;
  const int lr = lane & 15, lg = lane >> 4;

  f32x4 acc[4][4] = {};
  const size_t a_base = (size_t)(tm * 128) * K;
  const size_t b_base = (size_t)(tn * 128) * K;

  for (int k0 = 0; k0 < K; k0 += 64) {
    // stage 128x64 for A and B: 1024 chunks each, 4/thread, linear LDS dest,
    // inverse-swizzled global source (rule: both-sides-or-neither).
#pragma unroll
    for (int i = 0; i < 4; ++i) {
      int c = i * 256 + tid;
      int row = c >> 3, ch = c & 7;
      int sw = (ch ^ (row & 7)) * 8;
      gload_lds16(A + a_base + (size_t)row * K + k0 + sw, &As[c * 8]);
      gload_lds16(Bt + b_base + (size_t)row * K + k0 + sw, &Bs[c * 8]);
    }
    __syncthreads();
    bf16x8 af[4][2], bfr[4][2];
#pragma unroll
    for (int m = 0; m < 4; ++m) {
      int row = wr + m * 16 + lr;
#pragma unroll
      for (int kk = 0; kk < 2; ++kk)
        af[m][kk] = *(const bf16x8*)&As[(row * 64 + kk * 32 + lg * 8) ^ ((row & 7) << 3)];
    }
#pragma unroll
    for (int n = 0; n < 4; ++n) {
      int row = wc + n * 16 + lr;
#pragma unroll
      for (int kk = 0; kk < 2; ++kk)
        bfr[n][kk] = *(const bf16x8*)&Bs[(row * 64 + kk * 32 + lg * 8) ^ ((row & 7) << 3)];
    }
#pragma unroll
    for (int m = 0; m < 4; ++m)
#pragma unroll
      for (int n = 0; n < 4; ++n) {
        if constexpr (MODE == 0) {
          acc[m][n] = __builtin_amdgcn_mfma_f32_16x16x32_bf16(bfr[n][0], af[m][0], acc[m][n], 0, 0, 0);
          acc[m][n] = __builtin_amdgcn_mfma_f32_16x16x32_bf16(bfr[n][1], af[m][1], acc[m][n], 0, 0, 0);
        } else {
          acc[m][n] = __builtin_amdgcn_mfma_f32_16x16x32_bf16(af[m][0], bfr[n][0], acc[m][n], 0, 0, 0);
          acc[m][n] = __builtin_amdgcn_mfma_f32_16x16x32_bf16(af[m][1], bfr[n][1], acc[m][n], 0, 0, 0);
        }
      }
    __syncthreads();
  }

  if constexpr (MODE == 0) {
    // D[row=ncol][col=token]: lane holds token = m*16+lr, d = n*16+lg*4+r
    const int tok0 = tm * 128 + wr;
    const int col0 = tn * 128 + wc;
#pragma unroll
    for (int n = 0; n < 4; ++n) {
      int ncol = col0 + n * 16 + lg * 4;
      float4 bv = *(const float4*)&bias[ncol];
      int which = ncol >> 10, c = ncol & 1023;
      int h = c >> 6, d = c & 63;
#pragma unroll
      for (int m = 0; m < 4; ++m) {
        int tok = tok0 + m * 16 + lr;
        int b = tok >> 10, t = tok & 1023;
        union { u16 s[4]; uint2 v; } pk;
        pk.s[0] = f2bf(acc[m][n][0] + bv.x);
        pk.s[1] = f2bf(acc[m][n][1] + bv.y);
        pk.s[2] = f2bf(acc[m][n][2] + bv.z);
        pk.s[3] = f2bf(acc[m][n][3] + bv.w);
        *(uint2*)&out_q[(size_t)which * 8388608 + ((((size_t)b * 16 + h) * 1024 + t) << 6) + d] = pk.v;
      }
    }
  } else {
    const int row0 = tm * 128 + wr;
    const int col0 = tn * 128 + wc;
#pragma unroll
    for (int n = 0; n < 4; ++n) {
      int col = col0 + n * 16 + lr;
      float bv = bias[col];
#pragma unroll
      for (int m = 0; m < 4; ++m)
#pragma unroll
        for (int r = 0; r < 4; ++r) {
          int mrow = row0 + m * 16 + lg * 4 + r;
          out_f[(size_t)mrow * N + col] = acc[m][n][r] + bv;
        }
    }
  }
}

// ---------------- flash attention v3: swapped QK^T, KVBLK=128 --------------
// grid: 512 = 128 bh x 4 pairs (XCD-swizzled); 256 thr = 4 waves x 32 q-rows.
// Pass pair {p, 7-p}: exactly 9 KV tiles of 128 per block — balanced.
__global__ __launch_bounds__(256, 2) void attn_kernel(
    const u16* __restrict__ Qb, const u16* __restrict__ Kb,
    const u16* __restrict__ Vb, u16* __restrict__ yb) {
  __shared__ alignas(16) u16 Ks[128 * 64];      // [key][d], swizzled (stride 128B)
  __shared__ alignas(16) u16 Vt[64 * 128];      // [d][key], swizzled (stride 256B)
  __shared__ alignas(16) u16 Pl[4][32 * 128];   // per-wave [q][key], swizzled
  __shared__ float abuf[4][32];

  const int bid = blockIdx.x;
  const int xcd = bid & 7, j = bid >> 3;
  const int bh = ((j >> 2) << 3) + xcd;
  const int pr = j & 3;
  const size_t hb = (size_t)bh * 65536;
  const int tid = threadIdx.x, w = tid >> 6, lane = tid & 63;
  const int lr = lane & 15, lg = lane >> 4;
  const int b = bh >> 4, h = bh & 15;

  for (int pass = 0; pass < 2; ++pass) {
    const int qt = pass ? (7 - pr) : pr;
    const int q0 = qt * 128 + w * 32;

    bf16x8 qf[2][2];
#pragma unroll
    for (int mi = 0; mi < 2; ++mi)
#pragma unroll
      for (int ks = 0; ks < 2; ++ks)
        qf[mi][ks] = *(const bf16x8*)&Qb[hb + (size_t)(q0 + mi * 16 + lr) * 64 + ks * 32 + lg * 8];

    float m_run[2] = {-1e30f, -1e30f}, l_run[2] = {0.f, 0.f};
    f32x4 o[2][4] = {};

    const int nkt = qt + 1;
    for (int kt = 0; kt < nkt; ++kt) {
      // stage K tile [128][64]: 1024 chunks, 4/thread, 0-conflict swizzle
#pragma unroll
      for (int i = 0; i < 4; ++i) {
        int c = i * 256 + tid;
        int row = c >> 3, ch = c & 7;
        gload_lds16(Kb + hb + (size_t)(kt * 128 + row) * 64 + ((ch ^ (row & 7)) * 8), &Ks[c * 8]);
      }
      // stage V transposed: V[128key][64d] -> Vt[d][key^((d&7)<<3)]
      {
        int key = tid & 127, d0 = (tid >> 7) * 32;
        const u16* src = Vb + hb + (size_t)(kt * 128 + key) * 64 + d0;
        union { uint4 v[4]; u16 s[32]; } tmp;
        tmp.v[0] = *(const uint4*)src;
        tmp.v[1] = *(const uint4*)(src + 8);
        tmp.v[2] = *(const uint4*)(src + 16);
        tmp.v[3] = *(const uint4*)(src + 24);
#pragma unroll
        for (int jj = 0; jj < 32; ++jj) {
          int d = d0 + jj;
          Vt[d * 128 + (key ^ ((d & 7) << 3))] = tmp.s[jj];
        }
      }
      __syncthreads();

      {
        // QK^T swapped: S^T[key][query] = mfma(K_frag, Q_frag)
        f32x4 s[8][2] = {};  // [ni=key subtile][mi=query subtile]
        __builtin_amdgcn_s_setprio(1);
#pragma unroll
        for (int ni = 0; ni < 8; ++ni) {
          int krow = ni * 16 + lr;
          bf16x8 kf0 = *(const bf16x8*)&Ks[(krow * 64 + lg * 8) ^ ((krow & 7) << 3)];
          bf16x8 kf1 = *(const bf16x8*)&Ks[(krow * 64 + 32 + lg * 8) ^ ((krow & 7) << 3)];
#pragma unroll
          for (int mi = 0; mi < 2; ++mi) {
            s[ni][mi] = __builtin_amdgcn_mfma_f32_16x16x32_bf16(kf0, qf[mi][0], s[ni][mi], 0, 0, 0);
            s[ni][mi] = __builtin_amdgcn_mfma_f32_16x16x32_bf16(kf1, qf[mi][1], s[ni][mi], 0, 0, 0);
          }
        }
        __builtin_amdgcn_s_setprio(0);

        const bool need_mask = (kt == qt);  // only diagonal tile masks
        float alpha_l[2];
#pragma unroll
        for (int mi = 0; mi < 2; ++mi) {
          float v = -1e30f;
#pragma unroll
          for (int ni = 0; ni < 8; ++ni)
#pragma unroll
            for (int r = 0; r < 4; ++r) {
              float sv = s[ni][mi][r];
              if (need_mask) {
                int ka = kt * 128 + ni * 16 + lg * 4 + r;
                int qa = q0 + mi * 16 + lr;
                if (ka > qa) sv = -1e30f;
              }
              s[ni][mi][r] = sv;
              v = fmaxf(v, sv);
            }
          v = fmaxf(v, __shfl_xor(v, 16));
          v = fmaxf(v, __shfl_xor(v, 32));
          float mn = fmaxf(m_run[mi], v);
          float al = __expf((m_run[mi] - mn) * 0.125f);
          m_run[mi] = mn;
          float mh = mn * 0.125f;
          float rs = 0.f;
#pragma unroll
          for (int ni = 0; ni < 8; ++ni)
#pragma unroll
            for (int r = 0; r < 4; ++r) {
              float p = __expf(s[ni][mi][r] * 0.125f - mh);
              s[ni][mi][r] = p;
              rs += p;
            }
          rs += __shfl_xor(rs, 16);
          rs += __shfl_xor(rs, 32);
          l_run[mi] = l_run[mi] * al + rs;
          alpha_l[mi] = al;
        }
        if (lg == 0) {
          abuf[w][lr] = alpha_l[0];
          abuf[w][16 + lr] = alpha_l[1];
        }
        // write P to per-wave LDS [query][key], swizzled
#pragma unroll
        for (int mi = 0; mi < 2; ++mi) {
          int qrow = mi * 16 + lr;
          u16* dst = &Pl[w][qrow * 128];
          int sw = (qrow & 7) << 3;
#pragma unroll
          for (int ni = 0; ni < 8; ++ni)
#pragma unroll
            for (int r = 0; r < 4; ++r)
              dst[(ni * 16 + lg * 4 + r) ^ sw] = f2bf(s[ni][mi][r]);
        }
        asm volatile("s_waitcnt lgkmcnt(0)" ::: "memory");
        // rescale o rows by alpha
#pragma unroll
        for (int mi = 0; mi < 2; ++mi) {
          f32x4 av;
#pragma unroll
          for (int r = 0; r < 4; ++r) av[r] = abuf[w][mi * 16 + lg * 4 + r];
#pragma unroll
          for (int nd = 0; nd < 4; ++nd)
#pragma unroll
            for (int r = 0; r < 4; ++r) o[mi][nd][r] *= av[r];
        }
        // PV: O += P @ V  (K=128 over 4 kk-steps)
        __builtin_amdgcn_s_setprio(1);
#pragma unroll
        for (int ks = 0; ks < 4; ++ks) {
          bf16x8 pf[2];
#pragma unroll
          for (int mi = 0; mi < 2; ++mi) {
            int prow = mi * 16 + lr;
            pf[mi] = *(const bf16x8*)&Pl[w][prow * 128 + (((ks * 4 + lg) ^ (prow & 7)) * 8)];
          }
#pragma unroll
          for (int nd = 0; nd < 4; ++nd) {
            int vrow = nd * 16 + lr;
            bf16x8 vf = *(const bf16x8*)&Vt[vrow * 128 + (((ks * 4 + lg) ^ (vrow & 7)) * 8)];
#pragma unroll
            for (int mi = 0; mi < 2; ++mi)
              o[mi][nd] = __builtin_amdgcn_mfma_f32_16x16x32_bf16(pf[mi], vf, o[mi][nd], 0, 0, 0);
          }
        }
        __builtin_amdgcn_s_setprio(0);
      }
      __syncthreads();
    }

    // epilogue
    if (lg == 0) {
      abuf[w][lr] = l_run[0];
      abuf[w][16 + lr] = l_run[1];
    }
    asm volatile("s_waitcnt lgkmcnt(0)" ::: "memory");
#pragma unroll
    for (int mi = 0; mi < 2; ++mi) {
      f32x4 inv;
#pragma unroll
      for (int r = 0; r < 4; ++r) inv[r] = 1.f / abuf[w][mi * 16 + lg * 4 + r];
#pragma unroll
      for (int nd = 0; nd < 4; ++nd)
#pragma unroll
        for (int r = 0; r < 4; ++r) {
          int t = q0 + mi * 16 + lg * 4 + r;
          int c = h * 64 + nd * 16 + lr;
          yb[((size_t)b * 1024 + t) * 1024 + c] = f2bf(o[mi][nd][r] * inv[r]);
        }
    }
    __syncthreads();
  }
}

extern "C" void kernel_launch(void* const* d_in, const int* in_sizes, int n_in,
                              void* d_out, int out_size, void* d_ws, size_t ws_size,
                              hipStream_t stream) {
  const float* x = (const float*)d_in[0];
  const float* w_attn = (const float*)d_in[1];
  const float* b_attn = (const float*)d_in[2];
  const float* w_proj = (const float*)d_in[3];
  const float* b_proj = (const float*)d_in[4];
  float* out = (float*)d_out;

  u16* ws = (u16*)d_ws;
  u16* xb = ws;                  // 8192*1024 bf16 (reused as y after GEMM1)
  u16* watT = xb + 8388608;      // 3072*1024
  u16* wpT = watT + 3145728;     // 1024*1024
  u16* Qb = wpT + 1048576;       // 3 x 8388608 (Q,K,V contiguous)
  u16* yb = xb;

  cast_x_kernel<<<8192, 256, 0, stream>>>(x, xb, 2097152);
  {
    dim3 g(96, 32);
    transpose_cast_kernel<<<g, 256, 0, stream>>>(w_attn, watT, 1024, 3072);
  }
  {
    dim3 g(32, 32);
    transpose_cast_kernel<<<g, 256, 0, stream>>>(w_proj, wpT, 1024, 1024);
  }
  gemm_bf16<0><<<64 * 24, 256, 0, stream>>>(xb, watT, b_attn, Qb, nullptr, 8192, 3072, 1024);
  attn_kernel<<<512, 256, 0, stream>>>(Qb, Qb + 8388608, Qb + 2 * 8388608, yb);
  gemm_bf16<1><<<64 * 8, 256, 0, stream>>>(yb, wpT, b_proj, nullptr, out, 8192, 1024, 1024);
}